// Round 3
// baseline (1416.797 us; speedup 1.0000x reference)
//
#include <hip/hip_runtime.h>

// Batched Jacobi diffusion, B=8, 128x128, iters=1000.
// Round 16: split each batch across TWO blocks (upper rows 0-63, lower
// 64-127) -> 16 blocks on 16 CUs (pairs (b, b+8) share an XCD under the
// round-robin block->XCD map, so the per-step halo exchange is a same-L2
// release/acquire hop). Two effects:
//   1. VALU-issue work per CU halves (we were issue-bound at ~83% on 8 CUs).
//   2. Live set halves: 4 rows/wave -> 32 coef + 16 state + temps ~ 60 regs,
//      which FITS the 64-VGPR allocation the allocator insists on. This
//      structurally kills the ~64 v_accvgpr_read/step churn that r14/r15
//      attribute hints could not dislodge (VGPR_Count stayed 60-64).
// Cross-block halo: double-buffered (parity) row slots in d_ws + monotone
// version flags, release/acquire at agent scope. Flags re-zeroed each launch
// by a pre-kernel (graph-capture safe). Lockstep drift is absorbed by the
// 2-slot parity buffer; co-residency is trivial (16 blocks, 256 CUs).
//
// ws layout (floats): [0,2048)    haloDown[b][parity][128]  (upper row 63)
//                     [2048,4096) haloUp  [b][parity][128]  (lower row 64)
//          (ints)     [4096,4104) fD[b]   [4104,4112) fU[b]

#define GH 128
#define GW 128
#define NW 16      // waves per block
#define RPW 4      // rows per wave (halved by the split)
#define NT 1024

typedef float v2f __attribute__((ext_vector_type(2)));

__device__ __forceinline__ float dpp_shr1(float old_v, float src) {
    // lane l gets lane l-1's src; lane 0 (invalid) keeps old_v (= left clamp)
    return __int_as_float(__builtin_amdgcn_update_dpp(
        __float_as_int(old_v), __float_as_int(src), 0x138, 0xf, 0xf, false));
}
__device__ __forceinline__ float dpp_shl1(float old_v, float src) {
    // lane l gets lane l+1's src; lane 63 (invalid) keeps old_v (= right clamp)
    return __int_as_float(__builtin_amdgcn_update_dpp(
        __float_as_int(old_v), __float_as_int(src), 0x130, 0xf, 0xf, false));
}

// d = a * b.yx   (packed f32 mul; half-swap on src1 via op_sel, no mov needed)
__device__ __forceinline__ v2f pk_mul_yx(v2f a, v2f b) {
    v2f d;
    asm("v_pk_mul_f32 %0, %1, %2 op_sel:[0,1] op_sel_hi:[1,0]"
        : "=v"(d) : "v"(a), "v"(b));
    return d;
}
// d = a * b + c  (packed f32 fma)
__device__ __forceinline__ v2f pk_fma(v2f a, v2f b, v2f c) {
    v2f d;
    asm("v_pk_fma_f32 %0, %1, %2, %3 op_sel:[0,0,0] op_sel_hi:[1,1,1]"
        : "=v"(d) : "v"(a), "v"(b), "v"(c));
    return d;
}

__global__ void zero_flags_kernel(int* __restrict__ flags) {
    if (threadIdx.x < 16) flags[threadIdx.x] = 0;
}

__global__ void __launch_bounds__(NT)
jacobi_flux_kernel(const float* __restrict__ k_all,
                   const int* __restrict__ iters_p,
                   float* __restrict__ out,
                   float* __restrict__ ws)
{
    __shared__ __align__(16) v2f sTop[2][NW][64];   // 8 KB
    __shared__ __align__(16) v2f sBot[2][NW][64];   // 8 KB

    const int blk  = blockIdx.x;
    const int half = blk >> 3;          // 0 = rows 0..63, 1 = rows 64..127
    const int b    = blk & 7;           // batch
    const int tid  = threadIdx.x;
    const int l    = tid & 63;          // lane
    const int w    = tid >> 6;          // wave 0..15
    const int R0   = half * 64 + w * RPW;
    const int c0   = l * 2;
    const float* kb = k_all + b * GH * GW;
    const int iters = *iters_p;

    float* haloD = ws + b * 256;               // [parity][128]
    float* haloU = ws + 2048 + b * 256;
    int*   fD    = (int*)ws + 4096 + b;
    int*   fU    = (int*)ws + 4104 + b;

    const int wUp = (w == 0)      ? 0      : w - 1;
    const int wDn = (w == NW - 1) ? NW - 1 : w + 1;
    const bool gTop  = (half == 0 && w == 0);        // Dirichlet row 0
    const bool gBot  = (half == 1 && w == NW - 1);   // Dirichlet row 127
    const bool consU = (half == 0 && w == NW - 1);   // consumes haloU, produces haloD
    const bool consD = (half == 1 && w == 0);        // consumes haloD, produces haloU

    // ---- one-time: normalized face conductivities, packed for the
    //      regrouped stencil: rN, rS (vertical), cM=(cE.x,cW.y), cLR=(cW.x,cE.y)
    v2f rN[RPW], rS[RPW], cM[RPW], cLR[RPW];
    #pragma unroll
    for (int i = 0; i < RPW; ++i) {
        const int r  = R0 + i;
        const int ru = (r == 0)      ? 0      : r - 1;
        const int rd = (r == GH - 1) ? GH - 1 : r + 1;
        float v[2][4];
        #pragma unroll
        for (int jj = 0; jj < 2; ++jj) {
            const int c  = c0 + jj;
            const int cl = (c == 0)      ? 0      : c - 1;
            const int cr = (c == GW - 1) ? GW - 1 : c + 1;
            float kc = kb[r * GW + c];
            float kn = 0.5f * (kc + kb[ru * GW + c]);
            float ks = 0.5f * (kc + kb[rd * GW + c]);
            float kw = 0.5f * (kc + kb[r * GW + cl]);
            float ke = 0.5f * (kc + kb[r * GW + cr]);
            float inv = 1.0f / (kn + ks + kw + ke);
            v[jj][0] = kn * inv; v[jj][1] = ks * inv;
            v[jj][2] = kw * inv; v[jj][3] = ke * inv;
        }
        rN[i]  = (v2f){v[0][0], v[1][0]};
        rS[i]  = (v2f){v[0][1], v[1][1]};
        cM[i]  = (v2f){v[0][3], v[1][2]};   // (cE.x, cW.y) pairs with cc.yx
        cLR[i] = (v2f){v[0][2], v[1][3]};   // (cW.x, cE.y) pairs with (lfv,rtv)
    }

    // ---- state ----
    v2f A[RPW], B[RPW];
    #pragma unroll
    for (int i = 0; i < RPW; ++i)
        A[i] = (R0 + i == 0) ? (v2f){1.0f, 1.0f} : (v2f){0.0f, 0.0f};

    sTop[0][w][l] = A[0];
    sBot[0][w][l] = A[RPW - 1];
    // publish version 0 of the cross-block boundary rows (parity slot 0)
    if (consU) {   // upper w15: produce row 63
        ((v2f*)haloD)[l] = A[RPW - 1];
        if (l == 0)
            __hip_atomic_store(fD, 1, __ATOMIC_RELEASE, __HIP_MEMORY_SCOPE_AGENT);
    }
    if (consD) {   // lower w0: produce row 64
        ((v2f*)haloU)[l] = A[0];
        if (l == 0)
            __hip_atomic_store(fU, 1, __ATOMIC_RELEASE, __HIP_MEMORY_SCOPE_AGENT);
    }
    __syncthreads();

    auto step = [&](const v2f (&src)[RPW], v2f (&dst)[RPW], int rp, int wp, int t) {
        // vertical halos (issued first; latency hides under DPP + pk chain)
        v2f hu, hd;
        if (consD) {   // lower w0: needs row 63 (version t) from upper block
            while (__hip_atomic_load(fD, __ATOMIC_ACQUIRE,
                                     __HIP_MEMORY_SCOPE_AGENT) < t + 1) {}
            hu = ((const v2f*)(haloD + (t & 1) * 128))[l];
        } else {
            hu = sBot[rp][wUp][l];
        }
        if (consU) {   // upper w15: needs row 64 (version t) from lower block
            while (__hip_atomic_load(fU, __ATOMIC_ACQUIRE,
                                     __HIP_MEMORY_SCOPE_AGENT) < t + 1) {}
            hd = ((const v2f*)(haloU + (t & 1) * 128))[l];
        } else {
            hd = sTop[rp][wDn][l];
        }

        #pragma unroll
        for (int i = 0; i < RPW; ++i) {
            v2f cc = src[i];
            v2f s;
            s.x = dpp_shr1(cc.x, cc.y);   // left  neighbor (clamped at col 0)
            s.y = dpp_shl1(cc.y, cc.x);   // right neighbor (clamped at col 127)
            v2f up = (i == 0)       ? hu : src[i - 1];
            v2f dn = (i == RPW - 1) ? hd : src[i + 1];
            // dst = rN*up + rS*dn + cLR*(lfv,rtv) + cM*cc.yx  (all VOP3P)
            dst[i] = pk_fma(rN[i], up,
                     pk_fma(rS[i], dn,
                     pk_fma(cLR[i], s, pk_mul_yx(cM[i], cc))));
        }
        if (gTop) dst[0]       = (v2f){1.0f, 1.0f};   // Dirichlet row 0
        if (gBot) dst[RPW - 1] = (v2f){0.0f, 0.0f};   // Dirichlet row 127

        sTop[wp][w][l] = dst[0];
        sBot[wp][w][l] = dst[RPW - 1];

        // publish version t+1 of the boundary rows (parity slot (t+1)&1).
        // Safe: neighbor's flag >= t+1 (checked above) proves it finished
        // reading version t-1, the slot we're overwriting.
        if (consU) {
            ((v2f*)(haloD + ((t + 1) & 1) * 128))[l] = dst[RPW - 1];
            if (l == 0)
                __hip_atomic_store(fD, t + 2, __ATOMIC_RELEASE,
                                   __HIP_MEMORY_SCOPE_AGENT);
        }
        if (consD) {
            ((v2f*)(haloU + ((t + 1) & 1) * 128))[l] = dst[0];
            if (l == 0)
                __hip_atomic_store(fU, t + 2, __ATOMIC_RELEASE,
                                   __HIP_MEMORY_SCOPE_AGENT);
        }
        __syncthreads();
    };

    int t = 0;
    const int nPairs = iters >> 1;
    for (int it = 0; it < nPairs; ++it) {
        step(A, B, 0, 1, t); ++t;
        step(B, A, 1, 0, t); ++t;
    }
    if (iters & 1) {
        step(A, B, 0, 1, t); ++t;
        #pragma unroll
        for (int i = 0; i < RPW; ++i) A[i] = B[i];
    }

    // ---- flux at row 64: lower block's wave 0 holds rows 64..67 ----
    if (half == 1 && w == 0) {
        float partial = kb[64 * GW + c0]     * (A[1].x - A[0].x)
                      + kb[64 * GW + c0 + 1] * (A[1].y - A[0].y);
        #pragma unroll
        for (int off = 32; off > 0; off >>= 1)
            partial += __shfl_down(partial, off, 64);
        if (l == 0) out[b] = -partial;
    }
}

extern "C" void kernel_launch(void* const* d_in, const int* in_sizes, int n_in,
                              void* d_out, int out_size, void* d_ws, size_t ws_size,
                              hipStream_t stream)
{
    const float* k     = (const float*)d_in[0];
    const int*   iters = (const int*)d_in[1];
    float*       out   = (float*)d_out;
    int*         flags = (int*)d_ws + 4096;
    zero_flags_kernel<<<dim3(1), dim3(64), 0, stream>>>(flags);
    jacobi_flux_kernel<<<dim3(16), dim3(NT), 0, stream>>>(k, iters, out, (float*)d_ws);
}

// Round 5
// 587.004 us; speedup vs baseline: 2.4136x; 2.4136x over previous
//
#include <hip/hip_runtime.h>

// Batched Jacobi diffusion, B=8, 128x128, iters=1000. One 1024-thread block
// per batch (16 blocks/step cross-CU sync proved ~2000cy/step through the
// coherence point in r16 -- reverted). Wave-strip layout: 16 waves x 8 grid
// rows; lane owns a float2 column pair. VALU-issue-bound on 8 active CUs.
//
// Round 18 (= r17 resubmitted; bench infra failed, no counters): kill the
// v_accvgpr_read churn by actually unlocking the 128-reg arch budget.
// Evidence r13-r15: peak live set ~85 regs (64 loop-invariant coefs + ~10
// state + temps); allocator pinned arch VGPRs at 60-64 and parked the coefs
// in AGPRs -> 64 accvgpr_read/step = the measured ~134 instr/wave/step vs
// ~70 ideal. __launch_bounds__(1024) lowers to flat-work-group-size(1,1024);
// the min=1 lets the backend keep an 8-waves/EU (64-reg) target, which is
// why waves_per_eu(4,4) alone (r15: SGPR count moved, VGPR didn't) and
// launch_bounds(NT,4) (r14) both failed. Pin BOTH:
// flat_work_group_size(1024,1024) + waves_per_eu(4,4) -> budget is
// unambiguously 128 regs/wave; live set fits in arch VGPRs; AGPR traffic
// becomes structurally unnecessary. (Direct AGPR sources in VOP3P are
// impossible on CDNA -- no ACC-source encoding for regular VALU -- so
// fitting is the only cure.)
//
// Also: middle-first row order {2,3,4,5,6,0,1,7} hides the ~120cy
// post-barrier LDS halo-read latency under 5 halo-independent rows.
// Target per row: 2 DPP mov + 1 pk_mul + 3 pk_fma = 6 VALU slots.
//
// Fallback if VGPR_Count stays ~64: ghost-zone 2-block split (sync every
// G=16 steps, amortizing the r16 handshake 16x).

#define GH 128
#define GW 128
#define NW 16      // waves per block
#define RPW 8      // rows per wave
#define NT 1024

typedef float v2f __attribute__((ext_vector_type(2)));

// middle-first row order: halo-independent rows 2..6 first, then rows 0,1
// (consume hu), then row 7 (consumes hd).
__device__ constexpr int kOrd[RPW] = {2, 3, 4, 5, 6, 0, 1, 7};

__device__ __forceinline__ float dpp_shr1(float old_v, float src) {
    // lane l gets lane l-1's src; lane 0 (invalid) keeps old_v (= left clamp)
    return __int_as_float(__builtin_amdgcn_update_dpp(
        __float_as_int(old_v), __float_as_int(src), 0x138, 0xf, 0xf, false));
}
__device__ __forceinline__ float dpp_shl1(float old_v, float src) {
    // lane l gets lane l+1's src; lane 63 (invalid) keeps old_v (= right clamp)
    return __int_as_float(__builtin_amdgcn_update_dpp(
        __float_as_int(old_v), __float_as_int(src), 0x130, 0xf, 0xf, false));
}

// d = a * b.yx   (packed f32 mul; half-swap on src1 via op_sel, no mov needed)
__device__ __forceinline__ v2f pk_mul_yx(v2f a, v2f b) {
    v2f d;
    asm("v_pk_mul_f32 %0, %1, %2 op_sel:[0,1] op_sel_hi:[1,0]"
        : "=v"(d) : "v"(a), "v"(b));
    return d;
}
// d = a * b + c  (packed f32 fma)
__device__ __forceinline__ v2f pk_fma(v2f a, v2f b, v2f c) {
    v2f d;
    asm("v_pk_fma_f32 %0, %1, %2, %3 op_sel:[0,0,0] op_sel_hi:[1,1,1]"
        : "=v"(d) : "v"(a), "v"(b), "v"(c));
    return d;
}

__global__ void
__attribute__((amdgpu_flat_work_group_size(1024, 1024)))
__attribute__((amdgpu_waves_per_eu(4, 4)))
jacobi_flux_kernel(const float* __restrict__ k_all,
                   const int* __restrict__ iters_p,
                   float* __restrict__ out)
{
    __shared__ __align__(16) v2f sTop[2][NW][64];   // 16 KB
    __shared__ __align__(16) v2f sBot[2][NW][64];   // 16 KB

    const int b   = blockIdx.x;
    const int tid = threadIdx.x;
    const int l   = tid & 63;           // lane
    const int w   = tid >> 6;           // wave 0..15
    const int R0  = w * RPW;            // first grid row of my strip
    const int c0  = l * 2;              // first grid col of my pair
    const float* kb = k_all + b * GH * GW;
    const int iters = *iters_p;

    const int wUp = (w == 0)      ? 0      : w - 1;
    const int wDn = (w == NW - 1) ? NW - 1 : w + 1;
    const bool gTop = (w == 0);
    const bool gBot = (w == NW - 1);

    // ---- one-time: normalized face conductivities, packed for the
    //      regrouped stencil: rN, rS (vertical), cM=(cE.x,cW.y), cLR=(cW.x,cE.y)
    v2f rN[RPW], rS[RPW], cM[RPW], cLR[RPW];
    #pragma unroll
    for (int i = 0; i < RPW; ++i) {
        const int r  = R0 + i;
        const int ru = (r == 0)      ? 0      : r - 1;
        const int rd = (r == GH - 1) ? GH - 1 : r + 1;
        float v[2][4];
        #pragma unroll
        for (int jj = 0; jj < 2; ++jj) {
            const int c  = c0 + jj;
            const int cl = (c == 0)      ? 0      : c - 1;
            const int cr = (c == GW - 1) ? GW - 1 : c + 1;
            float kc = kb[r * GW + c];
            float kn = 0.5f * (kc + kb[ru * GW + c]);
            float ks = 0.5f * (kc + kb[rd * GW + c]);
            float kw = 0.5f * (kc + kb[r * GW + cl]);
            float ke = 0.5f * (kc + kb[r * GW + cr]);
            float inv = 1.0f / (kn + ks + kw + ke);
            v[jj][0] = kn * inv; v[jj][1] = ks * inv;
            v[jj][2] = kw * inv; v[jj][3] = ke * inv;
        }
        rN[i]  = (v2f){v[0][0], v[1][0]};
        rS[i]  = (v2f){v[0][1], v[1][1]};
        cM[i]  = (v2f){v[0][3], v[1][2]};   // (cE.x, cW.y) pairs with cc.yx
        cLR[i] = (v2f){v[0][2], v[1][3]};   // (cW.x, cE.y) pairs with (lfv,rtv)
    }

    // ---- state ----
    v2f A[RPW], B[RPW];
    #pragma unroll
    for (int i = 0; i < RPW; ++i)
        A[i] = (R0 + i == 0) ? (v2f){1.0f, 1.0f} : (v2f){0.0f, 0.0f};

    sTop[0][w][l] = A[0];
    sBot[0][w][l] = A[RPW - 1];
    __syncthreads();

    auto step = [&](const v2f (&src)[RPW], v2f (&dst)[RPW], int rp, int wp) {
        // halo loads issued first; consumed only by rows 0,1,7 which run
        // LAST (middle-first order) so the ~120cy LDS latency is hidden.
        v2f hu = sBot[rp][wUp][l];   // grid row R0-1
        v2f hd = sTop[rp][wDn][l];   // grid row R0+RPW

        #pragma unroll
        for (int j = 0; j < RPW; ++j) {
            const int i = kOrd[j];
            v2f cc = src[i];
            // (lfv, rtv): two DPP results, used only as a packed pair
            v2f s;
            s.x = dpp_shr1(cc.x, cc.y);   // left  neighbor (clamped at col 0)
            s.y = dpp_shl1(cc.y, cc.x);   // right neighbor (clamped at col 127)
            v2f up = (i == 0)       ? hu : src[i - 1];
            v2f dn = (i == RPW - 1) ? hd : src[i + 1];
            // dst = rN*up + rS*dn + cLR*(lfv,rtv) + cM*cc.yx  (all VOP3P)
            dst[i] = pk_fma(rN[i], up,
                     pk_fma(rS[i], dn,
                     pk_fma(cLR[i], s, pk_mul_yx(cM[i], cc))));
        }
        if (gTop) dst[0]       = (v2f){1.0f, 1.0f};   // Dirichlet row 0
        if (gBot) dst[RPW - 1] = (v2f){0.0f, 0.0f};   // Dirichlet row 127

        sTop[wp][w][l] = dst[0];
        sBot[wp][w][l] = dst[RPW - 1];
        __syncthreads();
    };

    const int nPairs = iters >> 1;
    for (int it = 0; it < nPairs; ++it) {
        step(A, B, 0, 1);
        step(B, A, 1, 0);
    }
    if (iters & 1) {
        step(A, B, 0, 1);
        #pragma unroll
        for (int i = 0; i < RPW; ++i) A[i] = B[i];
    }

    // ---- flux at row 64: wave 8 holds rows 64..71 (A[0]=r64, A[1]=r65) ----
    if (w == 8) {
        float partial = kb[64 * GW + c0]     * (A[1].x - A[0].x)
                      + kb[64 * GW + c0 + 1] * (A[1].y - A[0].y);
        #pragma unroll
        for (int off = 32; off > 0; off >>= 1)
            partial += __shfl_down(partial, off, 64);
        if (l == 0) out[b] = -partial;
    }
}

extern "C" void kernel_launch(void* const* d_in, const int* in_sizes, int n_in,
                              void* d_out, int out_size, void* d_ws, size_t ws_size,
                              hipStream_t stream)
{
    const float* k     = (const float*)d_in[0];
    const int*   iters = (const int*)d_in[1];
    float*       out   = (float*)d_out;
    jacobi_flux_kernel<<<dim3(8), dim3(NT), 0, stream>>>(k, iters, out);
}